// Round 1
// baseline (514.743 us; speedup 1.0000x reference)
//
#include <hip/hip_runtime.h>

// Problem constants (B=16, C=64, H=64, W=64, K=1024, D=64)
#define HWSZ   4096            // H*W
#define CCH    64              // C == D
#define KCB    1024            // num embeddings
#define NROW   65536           // B*H*W
#define NDTOT  4194304         // NROW * D  (elements of tensor output)

__global__ __launch_bounds__(64) void vq_init(float* out) {
    if (threadIdx.x == 0) { out[NDTOT] = 0.0f; out[NDTOT + 1] = 0.0f; }
}

__global__ __launch_bounds__(256, 4) void vq_main(const float* __restrict__ z,
                                                  const float* __restrict__ E,
                                                  float* __restrict__ out,
                                                  float* __restrict__ partial) {
    __shared__ float zs[64][65];     // zs[c][i] = z_flat[n0+i][c], padded (+1) vs bank conflicts
    __shared__ float e2s[KCB];       // ||e_k||^2
    __shared__ float wmin[4][64];
    __shared__ int   widx[4][64];
    __shared__ int   rowidx[64];
    __shared__ float wsum[4];

    const int t   = threadIdx.x;
    const int blk = blockIdx.x;          // 0..1023
    const int n0  = blk << 6;            // first row of this tile
    const int bb  = n0 >> 12;            // n0 / 4096 (batch index)
    const int hw0 = n0 & 4095;
    const float* zb = z + (size_t)bb * CCH * HWSZ + hw0;

    // ---- stage z tile (coalesced: lanes walk consecutive hw) ----
    #pragma unroll
    for (int j = 0; j < 16; ++j) {
        int f = t + 256 * j;
        int c = f >> 6, i = f & 63;
        zs[c][i] = zb[(size_t)c * HWSZ + i];
    }

    // ---- per-block ||e_k||^2 precompute (1.5% of main-loop FLOPs) ----
    for (int q = t; q < KCB; q += 256) {
        const float4* ep = (const float4*)(E + (size_t)q * 64);
        float s0 = 0.f, s1 = 0.f, s2 = 0.f, s3 = 0.f;
        #pragma unroll
        for (int c4 = 0; c4 < 16; c4 += 4) {
            float4 a = ep[c4 + 0], b = ep[c4 + 1], c = ep[c4 + 2], d = ep[c4 + 3];
            s0 += a.x * a.x + a.y * a.y + a.z * a.z + a.w * a.w;
            s1 += b.x * b.x + b.y * b.y + b.z * b.z + b.w * b.w;
            s2 += c.x * c.x + c.y * c.y + c.z * c.z + c.w * c.w;
            s3 += d.x * d.x + d.y * d.y + d.z * d.z + d.w * d.w;
        }
        e2s[q] = (s0 + s1) + (s2 + s3);
    }
    __syncthreads();

    const int i   = t & 63;   // row within tile
    const int wid = t >> 6;   // wave id -> k quarter

    // hoist this thread's z row into registers
    float zr[64];
    #pragma unroll
    for (int c = 0; c < 64; ++c) zr[c] = zs[c][i];

    float best = 3.4e38f;
    int   bidx = 0;
    const int k0 = wid << 8;                     // contiguous 256-k range per wave
    const float* Ew = E + (size_t)k0 * 64;

    for (int kk = 0; kk < 256; ++kk) {
        const float4* ek = (const float4*)(Ew + (size_t)kk * 64);  // wave-uniform -> broadcast
        float d0 = 0.f, d1 = 0.f, d2 = 0.f, d3 = 0.f;
        #pragma unroll
        for (int c4 = 0; c4 < 16; ++c4) {
            float4 a = ek[c4];
            d0 = fmaf(a.x, zr[4 * c4 + 0], d0);
            d1 = fmaf(a.y, zr[4 * c4 + 1], d1);
            d2 = fmaf(a.z, zr[4 * c4 + 2], d2);
            d3 = fmaf(a.w, zr[4 * c4 + 3], d3);
        }
        float dot  = (d0 + d1) + (d2 + d3);
        float dist = fmaf(-2.0f, dot, e2s[k0 + kk]);   // ||e||^2 - 2 z.e  (||z||^2 dropped)
        if (dist < best) { best = dist; bidx = k0 + kk; }   // strict <  => first-min
    }

    wmin[wid][i] = best;
    widx[wid][i] = bidx;
    __syncthreads();

    if (t < 64) {   // reduce the 4 per-wave candidates; strict < keeps smallest k on ties
        float m = wmin[0][t]; int ix = widx[0][t];
        #pragma unroll
        for (int w = 1; w < 4; ++w) {
            float v = wmin[w][t]; int x = widx[w][t];
            if (v < m) { m = v; ix = x; }
        }
        rowidx[t] = ix;
    }
    __syncthreads();

    // ---- output (raw-reshape semantics) + loss partial ----
    float lsum = 0.f;
    const size_t base = (size_t)blk * 4096;
    const float* zflat = z + base;
    float*       oflat = out + base;
    #pragma unroll
    for (int j = 0; j < 16; ++j) {
        int f  = t + 256 * j;
        int nl = f >> 6, d = f & 63;
        int k  = rowidx[nl];                       // wave-uniform
        float qv = E[(size_t)k * 64 + d];          // coalesced 256B row
        float zf = zs[d][nl];                      // z_flat[n0+nl][d]
        float df = qv - zf;
        lsum += df * df;
        float zraw = zflat[f];                     // z.flat[base+f] (BCHW layout!)
        oflat[f] = zraw + (qv - zraw);             // matches ref's z + (quantized - z)
    }

    // wave reduce (fixed order -> deterministic)
    #pragma unroll
    for (int off = 32; off >= 1; off >>= 1) lsum += __shfl_down(lsum, off, 64);
    if (i == 0) wsum[wid] = lsum;
    __syncthreads();
    if (t == 0) {
        float s = (wsum[0] + wsum[1]) + (wsum[2] + wsum[3]);
        if (partial) partial[blk] = s;
        else         atomicAdd(&out[NDTOT + 1], s);
    }
}

__global__ __launch_bounds__(256) void vq_fin(const float* __restrict__ partial,
                                              float* __restrict__ out, int use_ws) {
    if (use_ws) {
        __shared__ float ps[256];
        float s = 0.f;
        for (int q = threadIdx.x; q < KCB; q += 256) s += partial[q];
        ps[threadIdx.x] = s;
        __syncthreads();
        for (int st = 128; st >= 1; st >>= 1) {
            if (threadIdx.x < st) ps[threadIdx.x] += ps[threadIdx.x + st];
            __syncthreads();
        }
        if (threadIdx.x == 0) {
            float mse = ps[0] / (float)NDTOT;
            out[NDTOT]     = 0.25f * mse;   // commitment_loss (return order: first)
            out[NDTOT + 1] = mse;           // codebook_loss
        }
    } else {
        if (threadIdx.x == 0) {
            float mse = out[NDTOT + 1] / (float)NDTOT;
            out[NDTOT]     = 0.25f * mse;
            out[NDTOT + 1] = mse;
        }
    }
}

extern "C" void kernel_launch(void* const* d_in, const int* in_sizes, int n_in,
                              void* d_out, int out_size, void* d_ws, size_t ws_size,
                              hipStream_t stream) {
    const float* z = (const float*)d_in[0];
    const float* E = (const float*)d_in[1];
    float* out = (float*)d_out;
    float* partial = (ws_size >= KCB * sizeof(float)) ? (float*)d_ws : nullptr;
    int use_ws = (partial != nullptr) ? 1 : 0;

    hipLaunchKernelGGL(vq_init, dim3(1), dim3(64), 0, stream, out);
    hipLaunchKernelGGL(vq_main, dim3(1024), dim3(256), 0, stream, z, E, out, partial);
    hipLaunchKernelGGL(vq_fin, dim3(1), dim3(256), 0, stream, partial, out, use_ws);
}

// Round 2
// 76.361 us; speedup vs baseline: 6.7409x; 6.7409x over previous
//
#include <hip/hip_runtime.h>

// Problem constants (B=16, C=64, H=64, W=64, K=1024, D=64)
#define HWSZ   4096
#define CCH    64
#define KCB    1024
#define NROW   65536
#define NDTOT  4194304

typedef __attribute__((ext_vector_type(8))) short short8;
typedef __attribute__((ext_vector_type(4))) float f32x4;

__device__ __forceinline__ unsigned short f2bf(float x) {
    union { float f; unsigned u; } v; v.f = x;
    unsigned r = (v.u + 0x7fffu + ((v.u >> 16) & 1u)) >> 16;
    return (unsigned short)r;
}

// ---------- prep: E fp32 -> bf16 (row-major K x D) + he2[k] = 0.5*||e_k||^2 ----------
__global__ __launch_bounds__(256) void vq_prep(const float* __restrict__ E,
                                               unsigned int* __restrict__ Ebf, // packed 2xbf16
                                               float* __restrict__ he2) {
    int k = blockIdx.x * 256 + threadIdx.x;   // 0..1023
    const float4* ep = (const float4*)(E + (size_t)k * 64);
    float s = 0.f;
    #pragma unroll
    for (int c4 = 0; c4 < 16; ++c4) {
        float4 a = ep[c4];
        s += a.x * a.x + a.y * a.y + a.z * a.z + a.w * a.w;
        unsigned lo = (unsigned)f2bf(a.x) | ((unsigned)f2bf(a.y) << 16);
        unsigned hi = (unsigned)f2bf(a.z) | ((unsigned)f2bf(a.w) << 16);
        Ebf[(size_t)k * 32 + c4 * 2 + 0] = lo;
        Ebf[(size_t)k * 32 + c4 * 2 + 1] = hi;
    }
    he2[k] = 0.5f * s;
}

// ---------- main: MFMA distance scan + argmin + output + loss partial ----------
__global__ __launch_bounds__(256, 2) void vq_mfma(const float* __restrict__ z,
                                                  const float* __restrict__ E,
                                                  const short* __restrict__ Ebf,
                                                  const float* __restrict__ he2g,
                                                  float* __restrict__ out,
                                                  float* __restrict__ partial) {
    __shared__ float zs[64][65];     // zs[c][i] = z_flat[n0+i][c]
    __shared__ float he2s[KCB];
    __shared__ float wbest[4][64];
    __shared__ int   widxs[4][64];
    __shared__ int   rowidx[64];
    __shared__ float wsum[4];

    const int t   = threadIdx.x;
    const int blk = blockIdx.x;
    const int n0  = blk << 6;
    const int bb  = n0 >> 12;
    const int hw0 = n0 & 4095;
    const float* zb = z + (size_t)bb * CCH * HWSZ + hw0;

    // stage z tile (coalesced)
    #pragma unroll
    for (int j = 0; j < 16; ++j) {
        int f = t + 256 * j;
        int c = f >> 6, i = f & 63;
        zs[c][i] = zb[(size_t)c * HWSZ + i];
    }
    for (int q = t; q < KCB; q += 256) he2s[q] = he2g[q];
    __syncthreads();

    const int wid  = t >> 6;
    const int lane = t & 63;
    const int col  = lane & 15;     // code col / A row within 16-tile
    const int g    = lane >> 4;     // k-group

    // A-frags: rows rt*16+col, k = ch*32 + g*8 + j ; value = -z (so acc = -dot)
    short8 af[4][2];
    #pragma unroll
    for (int rt = 0; rt < 4; ++rt) {
        const int i = rt * 16 + col;
        #pragma unroll
        for (int ch = 0; ch < 2; ++ch) {
            short8 a;
            #pragma unroll
            for (int j = 0; j < 8; ++j) {
                int d = ch * 32 + g * 8 + j;
                a[j] = (short)f2bf(-zs[d][i]);
            }
            af[rt][ch] = a;
        }
    }

    float best[4][4];
    int   bidx[4][4];
    #pragma unroll
    for (int rt = 0; rt < 4; ++rt)
        #pragma unroll
        for (int r = 0; r < 4; ++r) { best[rt][r] = 3.4e38f; bidx[rt][r] = 0; }

    // B-frag pointer: code row (wid*256 + ct*16 + col), k-offset g*8 (+32 for chunk 1)
    const short* pB = Ebf + (size_t)(wid * 256 + col) * 64 + g * 8;
    short8 bc0 = *(const short8*)(pB);
    short8 bc1 = *(const short8*)(pB + 32);

    #pragma unroll
    for (int ct = 0; ct < 16; ++ct) {
        short8 bn0 = bc0, bn1 = bc1;
        if (ct < 15) {
            bn0 = *(const short8*)(pB + (ct + 1) * 1024);
            bn1 = *(const short8*)(pB + (ct + 1) * 1024 + 32);
        }
        const int code = wid * 256 + ct * 16 + col;
        const float he2v = he2s[code];
        #pragma unroll
        for (int rt = 0; rt < 4; ++rt) {
            f32x4 acc = {0.f, 0.f, 0.f, 0.f};
            acc = __builtin_amdgcn_mfma_f32_16x16x32_bf16(af[rt][0], bc0, acc, 0, 0, 0);
            acc = __builtin_amdgcn_mfma_f32_16x16x32_bf16(af[rt][1], bc1, acc, 0, 0, 0);
            #pragma unroll
            for (int r = 0; r < 4; ++r) {
                float m = he2v + acc[r];          // 0.5||e||^2 - z.e  (monotone in dist)
                bool c = m < best[rt][r];
                best[rt][r] = c ? m : best[rt][r];
                bidx[rt][r] = c ? code : bidx[rt][r];
            }
        }
        bc0 = bn0; bc1 = bn1;
    }

    // per-row reduce across the 16 lanes of each group (rows rt*16 + g*4 + r)
    #pragma unroll
    for (int rt = 0; rt < 4; ++rt) {
        #pragma unroll
        for (int r = 0; r < 4; ++r) {
            float d = best[rt][r]; int ix = bidx[rt][r];
            #pragma unroll
            for (int mask = 1; mask < 16; mask <<= 1) {
                float od = __shfl_xor(d, mask, 64);
                int   oi = __shfl_xor(ix, mask, 64);
                if (od < d || (od == d && oi < ix)) { d = od; ix = oi; }
            }
            if (col == 0) {
                int row = rt * 16 + g * 4 + r;
                wbest[wid][row] = d;
                widxs[wid][row] = ix;
            }
        }
    }
    __syncthreads();

    if (t < 64) {   // cross-wave (waves hold disjoint ascending code ranges)
        float m = wbest[0][t]; int ix = widxs[0][t];
        #pragma unroll
        for (int w = 1; w < 4; ++w) {
            float v = wbest[w][t]; int x = widxs[w][t];
            if (v < m || (v == m && x < ix)) { m = v; ix = x; }
        }
        rowidx[t] = ix;
    }
    __syncthreads();

    // ---- output (raw-reshape semantics) + loss partial ----
    float lsum = 0.f;
    const size_t base = (size_t)blk * 4096;
    const float* zflat = z + base;
    float*       oflat = out + base;
    #pragma unroll
    for (int j = 0; j < 16; ++j) {
        int f  = t + 256 * j;
        int nl = f >> 6, d = f & 63;
        int k  = rowidx[nl];
        float qv = E[(size_t)k * 64 + d];
        float zf = zs[d][nl];
        float df = qv - zf;
        lsum += df * df;
        float zraw = zflat[f];
        oflat[f] = zraw + (qv - zraw);
    }

    #pragma unroll
    for (int off = 32; off >= 1; off >>= 1) lsum += __shfl_down(lsum, off, 64);
    if (lane == 0) wsum[wid] = lsum;
    __syncthreads();
    if (t == 0) partial[blk] = (wsum[0] + wsum[1]) + (wsum[2] + wsum[3]);
}

// ---------- fallback fp32 path (round-1 kernel, used only if ws too small) ----------
__global__ __launch_bounds__(64) void vq_init(float* out) {
    if (threadIdx.x == 0) { out[NDTOT] = 0.0f; out[NDTOT + 1] = 0.0f; }
}

__global__ __launch_bounds__(256, 4) void vq_main_fp32(const float* __restrict__ z,
                                                       const float* __restrict__ E,
                                                       float* __restrict__ out,
                                                       float* __restrict__ partial) {
    __shared__ float zs[64][65];
    __shared__ float e2s[KCB];
    __shared__ float wmin[4][64];
    __shared__ int   widx[4][64];
    __shared__ int   rowidx[64];
    __shared__ float wsum[4];

    const int t   = threadIdx.x;
    const int blk = blockIdx.x;
    const int n0  = blk << 6;
    const int bb  = n0 >> 12;
    const int hw0 = n0 & 4095;
    const float* zb = z + (size_t)bb * CCH * HWSZ + hw0;

    #pragma unroll
    for (int j = 0; j < 16; ++j) {
        int f = t + 256 * j;
        int c = f >> 6, i = f & 63;
        zs[c][i] = zb[(size_t)c * HWSZ + i];
    }
    for (int q = t; q < KCB; q += 256) {
        const float4* ep = (const float4*)(E + (size_t)q * 64);
        float s0 = 0.f;
        #pragma unroll
        for (int c4 = 0; c4 < 16; ++c4) {
            float4 a = ep[c4];
            s0 += a.x * a.x + a.y * a.y + a.z * a.z + a.w * a.w;
        }
        e2s[q] = s0;
    }
    __syncthreads();

    const int i   = t & 63;
    const int wid = t >> 6;
    float zr[64];
    #pragma unroll
    for (int c = 0; c < 64; ++c) zr[c] = zs[c][i];

    float best = 3.4e38f;
    int   bi = 0;
    const int k0 = wid << 8;
    const float* Ew = E + (size_t)k0 * 64;
    for (int kk = 0; kk < 256; ++kk) {
        const float4* ek = (const float4*)(Ew + (size_t)kk * 64);
        float d0 = 0.f, d1 = 0.f, d2 = 0.f, d3 = 0.f;
        #pragma unroll
        for (int c4 = 0; c4 < 16; ++c4) {
            float4 a = ek[c4];
            d0 = fmaf(a.x, zr[4 * c4 + 0], d0);
            d1 = fmaf(a.y, zr[4 * c4 + 1], d1);
            d2 = fmaf(a.z, zr[4 * c4 + 2], d2);
            d3 = fmaf(a.w, zr[4 * c4 + 3], d3);
        }
        float dot  = (d0 + d1) + (d2 + d3);
        float dist = fmaf(-2.0f, dot, e2s[k0 + kk]);
        if (dist < best) { best = dist; bi = k0 + kk; }
    }
    wmin[wid][i] = best; widx[wid][i] = bi;
    __syncthreads();
    if (t < 64) {
        float m = wmin[0][t]; int ix = widx[0][t];
        #pragma unroll
        for (int w = 1; w < 4; ++w) {
            float v = wmin[w][t]; int x = widx[w][t];
            if (v < m) { m = v; ix = x; }
        }
        rowidx[t] = ix;
    }
    __syncthreads();

    float lsum = 0.f;
    const size_t base = (size_t)blk * 4096;
    const float* zflat = z + base;
    float*       oflat = out + base;
    #pragma unroll
    for (int j = 0; j < 16; ++j) {
        int f  = t + 256 * j;
        int nl = f >> 6, d = f & 63;
        int k  = rowidx[nl];
        float qv = E[(size_t)k * 64 + d];
        float zf = zs[d][nl];
        float df = qv - zf;
        lsum += df * df;
        float zraw = zflat[f];
        oflat[f] = zraw + (qv - zraw);
    }
    #pragma unroll
    for (int off = 32; off >= 1; off >>= 1) lsum += __shfl_down(lsum, off, 64);
    if (i == 0) wsum[wid] = lsum;
    __syncthreads();
    if (t == 0) {
        float s = (wsum[0] + wsum[1]) + (wsum[2] + wsum[3]);
        if (partial) partial[blk] = s;
        else         atomicAdd(&out[NDTOT + 1], s);
    }
}

__global__ __launch_bounds__(256) void vq_fin(const float* __restrict__ partial,
                                              float* __restrict__ out, int use_ws) {
    if (use_ws) {
        __shared__ float ps[256];
        float s = 0.f;
        for (int q = threadIdx.x; q < KCB; q += 256) s += partial[q];
        ps[threadIdx.x] = s;
        __syncthreads();
        for (int st = 128; st >= 1; st >>= 1) {
            if (threadIdx.x < st) ps[threadIdx.x] += ps[threadIdx.x + st];
            __syncthreads();
        }
        if (threadIdx.x == 0) {
            float mse = ps[0] / (float)NDTOT;
            out[NDTOT]     = 0.25f * mse;   // commitment_loss
            out[NDTOT + 1] = mse;           // codebook_loss
        }
    } else {
        if (threadIdx.x == 0) {
            float mse = out[NDTOT + 1] / (float)NDTOT;
            out[NDTOT]     = 0.25f * mse;
            out[NDTOT + 1] = mse;
        }
    }
}

extern "C" void kernel_launch(void* const* d_in, const int* in_sizes, int n_in,
                              void* d_out, int out_size, void* d_ws, size_t ws_size,
                              hipStream_t stream) {
    const float* z = (const float*)d_in[0];
    const float* E = (const float*)d_in[1];
    float* out = (float*)d_out;

    const size_t EBF_BYTES = (size_t)KCB * 64 * 2;          // 131072
    const size_t need = EBF_BYTES + 4096 + 4096;            // Ebf + he2 + partial

    if (ws_size >= need) {
        unsigned int* EbfU = (unsigned int*)d_ws;
        short* Ebf  = (short*)d_ws;
        float* he2  = (float*)((char*)d_ws + EBF_BYTES);
        float* partial = (float*)((char*)d_ws + EBF_BYTES + 4096);
        hipLaunchKernelGGL(vq_prep, dim3(4), dim3(256), 0, stream, E, EbfU, he2);
        hipLaunchKernelGGL(vq_mfma, dim3(1024), dim3(256), 0, stream,
                           z, E, Ebf, he2, out, partial);
        hipLaunchKernelGGL(vq_fin, dim3(1), dim3(256), 0, stream, partial, out, 1);
    } else {
        float* partial = (ws_size >= KCB * sizeof(float)) ? (float*)d_ws : nullptr;
        int use_ws = (partial != nullptr) ? 1 : 0;
        hipLaunchKernelGGL(vq_init, dim3(1), dim3(64), 0, stream, out);
        hipLaunchKernelGGL(vq_main_fp32, dim3(1024), dim3(256), 0, stream, z, E, out, partial);
        hipLaunchKernelGGL(vq_fin, dim3(1), dim3(256), 0, stream, partial, out, use_ws);
    }
}